// Round 6
// baseline (309.470 us; speedup 1.0000x reference)
//
#include <hip/hip_runtime.h>
#include <cstddef>
#include <cstdint>

#define B_ 4
#define C_ 256
#define N_ 4096
#define QK_BF 1048576                    /* bf16 elems: qk_t [b][N][64] (q ch 0..31 scaled by log2e, k ch 32..63) */
#define D_BF  4194304                    /* bf16 elems: [b][256][N] y3 -> d                       */
#define D_OFF_B   ((size_t)QK_BF * 2)    /* 2 MB  */
#define SUM_OFF_B (D_OFF_B + (size_t)D_BF * 2)  /* 10 MB: sum[320],sumsq[320],sc[320],bi[320] */
#define ML_OFF_B  (SUM_OFF_B + 1280 * 4)        /* mpart[4][b][n], lpart[4][b][n]: 2x65536 floats */
#define XH_OFF_B  (ML_OFF_B + 524288)           /* xt hi [b][n][256] bf16: 8 MB */
#define XL_OFF_B  (XH_OFF_B + (size_t)8 * 1024 * 1024)
#define WH_OFF_B  (XL_OFF_B + (size_t)8 * 1024 * 1024)  /* w hi [320][256] bf16 */
#define WL_OFF_B  (WH_OFF_B + 163840)
#define LOG2E 1.4426950408889634f

typedef unsigned short bfraw;
typedef __attribute__((ext_vector_type(8))) short short8;
typedef __attribute__((ext_vector_type(4))) float float4v;
typedef __attribute__((ext_vector_type(4))) bfraw bfraw4;

__device__ inline bfraw f2bf(float f) {
    union { float f; uint32_t u; } c; c.f = f;
    uint32_t u = c.u;
    u += 0x7fffu + ((u >> 16) & 1u);     // RNE
    return (bfraw)(u >> 16);
}
__device__ inline float bf2f(bfraw h) {
    union { uint32_t u; float f; } c; c.u = ((uint32_t)h) << 16;
    return c.f;
}
#if __has_builtin(__builtin_amdgcn_exp2f)
__device__ inline float EXP2(float x) { return __builtin_amdgcn_exp2f(x); }
#else
__device__ inline float EXP2(float x) { return exp2f(x); }
#endif
// pack two non-negative floats to bf16 pair (round-half-up), a in low half
__device__ inline uint32_t pack2(float a, float b) {
    union { float f; uint32_t u; } ca, cb; ca.f = a; cb.f = b;
#if __has_builtin(__builtin_amdgcn_perm)
    return __builtin_amdgcn_perm(cb.u + 0x8000u, ca.u + 0x8000u, 0x07060302u);
#else
    return ((ca.u + 0x8000u) >> 16) | ((cb.u + 0x8000u) & 0xffff0000u);
#endif
}

// ---------------------------------------------------------------------------
// Kernel 0: zero stats accumulators.
// ---------------------------------------------------------------------------
__global__ void zero_kernel(float* __restrict__ sums) {
    for (int i = threadIdx.x; i < 640; i += 256) sums[i] = 0.f;
}

// ---------------------------------------------------------------------------
// Kernel 0b: out = x  (flash adds partial O via atomics).
// ---------------------------------------------------------------------------
__global__ __launch_bounds__(256) void initout_kernel(
    const float* __restrict__ x, float* __restrict__ out) {
    size_t i = ((size_t)blockIdx.x * 256 + threadIdx.x) * 4;
    *(float4*)&out[i] = *(const float4*)&x[i];
}

// ---------------------------------------------------------------------------
// Kernel 1a: split w1|w2|w3 into bf16 hi/lo planes [320][256].
// ---------------------------------------------------------------------------
__global__ __launch_bounds__(256) void wsplit_kernel(
    const float* __restrict__ w1, const float* __restrict__ w2,
    const float* __restrict__ w3, uint8_t* __restrict__ wsb)
{
    bfraw* wh = (bfraw*)(wsb + WH_OFF_B);
    bfraw* wl = (bfraw*)(wsb + WL_OFF_B);
    int idx4 = (blockIdx.x * 256 + threadIdx.x) * 4;
    int ch = idx4 >> 8, k = idx4 & 255;
    const float* wr = (ch < 32) ? (w1 + ch * C_)
                      : (ch < 64) ? (w2 + (ch - 32) * C_)
                                  : (w3 + (ch - 64) * C_);
    float4 v = *(const float4*)&wr[k];
    float va[4] = {v.x, v.y, v.z, v.w};
    bfraw4 h, l;
#pragma unroll
    for (int j = 0; j < 4; ++j) {
        h[j] = f2bf(va[j]);
        l[j] = f2bf(va[j] - bf2f(h[j]));
    }
    *(bfraw4*)&wh[idx4] = h;
    *(bfraw4*)&wl[idx4] = l;
}

// ---------------------------------------------------------------------------
// Kernel 1b: transpose+split x -> xt_hi/xt_lo [b][n][256cin] bf16.
// ---------------------------------------------------------------------------
__global__ __launch_bounds__(256) void xtsplit_kernel(
    const float* __restrict__ x, uint8_t* __restrict__ wsb)
{
    __shared__ float Ls[64][65];
    bfraw* xh = (bfraw*)(wsb + XH_OFF_B);
    bfraw* xl = (bfraw*)(wsb + XL_OFF_B);
    const int id = blockIdx.x;
    const int b  = id >> 8;
    const int c0 = ((id >> 6) & 3) << 6;
    const int n0 = (id & 63) << 6;
    const int t  = threadIdx.x;
    {
        int cl = t >> 4, nc = (t & 15) << 2;
#pragma unroll
        for (int i = 0; i < 4; ++i) {
            float4 v = *(const float4*)&x[((size_t)b * C_ + c0 + cl + i * 16) * N_ + n0 + nc];
            Ls[cl + i * 16][nc + 0] = v.x;
            Ls[cl + i * 16][nc + 1] = v.y;
            Ls[cl + i * 16][nc + 2] = v.z;
            Ls[cl + i * 16][nc + 3] = v.w;
        }
    }
    __syncthreads();
    int nl = t >> 2, seg = t & 3;
    bfraw hb[16], lb[16];
#pragma unroll
    for (int j = 0; j < 16; ++j) {
        float v = Ls[seg * 16 + j][nl];
        bfraw h = f2bf(v);
        hb[j] = h;
        lb[j] = f2bf(v - bf2f(h));
    }
    size_t base = ((size_t)b * N_ + n0 + nl) * 256 + c0 + seg * 16;
    *(short8*)&xh[base]     = *(short8*)&hb[0];
    *(short8*)&xh[base + 8] = *(short8*)&hb[8];
    *(short8*)&xl[base]     = *(short8*)&lb[0];
    *(short8*)&xl[base + 8] = *(short8*)&lb[8];
}

// ---------------------------------------------------------------------------
// Kernel 1c: MFMA ygemm (3-term bf16 split), fragments direct from L2.
// ---------------------------------------------------------------------------
__global__ __launch_bounds__(256, 2) void ygemm_kernel(uint8_t* __restrict__ wsb)
{
    const bfraw* xh = (const bfraw*)(wsb + XH_OFF_B);
    const bfraw* xl = (const bfraw*)(wsb + XL_OFF_B);
    const bfraw* wh = (const bfraw*)(wsb + WH_OFF_B);
    const bfraw* wl = (const bfraw*)(wsb + WL_OFF_B);
    bfraw* qkt = (bfraw*)wsb;
    bfraw* db  = (bfraw*)(wsb + D_OFF_B);
    float* sums  = (float*)(wsb + SUM_OFF_B);
    float* sumsq = sums + 320;
    __shared__ float redS[4][64], redQ[4][64];

    const int bx = blockIdx.x;
    const int by = blockIdx.y;
    const int b  = bx >> 5;
    const int n0 = (bx << 7) & (N_ - 1);
    const int t = threadIdx.x, w = t >> 6, l = t & 63, lq = l & 15, lg = l >> 4;
    const int nw = n0 + w * 32;

    float4v acc[4][2];
#pragma unroll
    for (int i = 0; i < 4; ++i)
#pragma unroll
        for (int j = 0; j < 2; ++j) acc[i][j] = (float4v){0.f, 0.f, 0.f, 0.f};

    for (int s = 0; s < 8; ++s) {
        const int k0 = s * 32;
        short8 ah[4], al[4], bh[2], bl[2];
#pragma unroll
        for (int ct = 0; ct < 4; ++ct) {
            size_t off = (size_t)(by * 64 + ct * 16 + lq) * 256 + k0 + lg * 8;
            ah[ct] = *(const short8*)&wh[off];
            al[ct] = *(const short8*)&wl[off];
        }
#pragma unroll
        for (int nt = 0; nt < 2; ++nt) {
            size_t off = ((size_t)b * N_ + nw + nt * 16 + lq) * 256 + k0 + lg * 8;
            bh[nt] = *(const short8*)&xh[off];
            bl[nt] = *(const short8*)&xl[off];
        }
#pragma unroll
        for (int ct = 0; ct < 4; ++ct)
#pragma unroll
            for (int nt = 0; nt < 2; ++nt) {
                acc[ct][nt] = __builtin_amdgcn_mfma_f32_16x16x32_bf16(ah[ct], bh[nt], acc[ct][nt], 0, 0, 0);
                acc[ct][nt] = __builtin_amdgcn_mfma_f32_16x16x32_bf16(al[ct], bh[nt], acc[ct][nt], 0, 0, 0);
                acc[ct][nt] = __builtin_amdgcn_mfma_f32_16x16x32_bf16(ah[ct], bl[nt], acc[ct][nt], 0, 0, 0);
            }
    }
#pragma unroll
    for (int ct = 0; ct < 4; ++ct) {
        float sv[4], qv[4];
#pragma unroll
        for (int r = 0; r < 4; ++r) {
            float a0 = acc[ct][0][r], a1 = acc[ct][1][r];
            sv[r] = a0 + a1;
            qv[r] = a0 * a0 + a1 * a1;
#pragma unroll
            for (int m = 1; m < 16; m <<= 1) {
                sv[r] += __shfl_xor(sv[r], m);
                qv[r] += __shfl_xor(qv[r], m);
            }
        }
        if (lq == 0) {
#pragma unroll
            for (int r = 0; r < 4; ++r) {
                redS[w][ct * 16 + lg * 4 + r] = sv[r];
                redQ[w][ct * 16 + lg * 4 + r] = qv[r];
            }
        }
    }
    __syncthreads();
    if (t < 64) {
        float s = redS[0][t] + redS[1][t] + redS[2][t] + redS[3][t];
        float q = redQ[0][t] + redQ[1][t] + redQ[2][t] + redQ[3][t];
        atomicAdd(&sums[by * 64 + t], s);
        atomicAdd(&sumsq[by * 64 + t], q);
    }
    if (by == 0) {
#pragma unroll
        for (int ct = 0; ct < 4; ++ct)
#pragma unroll
            for (int nt = 0; nt < 2; ++nt)
#pragma unroll
                for (int r = 0; r < 4; ++r) {
                    int ch = ct * 16 + lg * 4 + r;
                    int n = nw + nt * 16 + lq;
                    qkt[(((size_t)b * N_ + n) << 6) + ch] = f2bf(acc[ct][nt][r]);
                }
    } else {
#pragma unroll
        for (int ct = 0; ct < 4; ++ct)
#pragma unroll
            for (int nt = 0; nt < 2; ++nt)
#pragma unroll
                for (int r = 0; r < 4; ++r) {
                    int ch = by * 64 - 64 + ct * 16 + lg * 4 + r;
                    int n = nw + nt * 16 + lq;
                    db[((size_t)b * C_ + ch) * N_ + n] = f2bf(acc[ct][nt][r]);
                }
    }
}

// ---------------------------------------------------------------------------
// Kernel 2: finalize BN -> folded scale/bias; q channels (<32) pre-scaled by
// log2(e) so QK^T scores come out in log2 domain.
// ---------------------------------------------------------------------------
__global__ void finalize_kernel(
    const float* __restrict__ g1, const float* __restrict__ b1,
    const float* __restrict__ g2, const float* __restrict__ b2,
    const float* __restrict__ g3, const float* __restrict__ b3,
    float* __restrict__ sums)
{
    int ch = threadIdx.x;
    if (ch >= 320) return;
    const float inv = 1.0f / (float)(B_ * N_);
    float mean = sums[ch] * inv;
    float var = sums[320 + ch] * inv - mean * mean;
    float g, bb;
    if (ch < 32)      { g = g1[ch];      bb = b1[ch]; }
    else if (ch < 64) { g = g2[ch - 32]; bb = b2[ch - 32]; }
    else              { g = g3[ch - 64]; bb = b3[ch - 64]; }
    float sc = g * rsqrtf(var + 1e-5f);
    float bi = bb - sc * mean;
    if (ch < 32) { sc *= LOG2E; bi *= LOG2E; }   // relu(z)*k == relu(k*z), k>0
    sums[640 + ch] = sc;
    sums[960 + ch] = bi;
}

// ---------------------------------------------------------------------------
// Kernel 3: in-place bf16 relu(sc*y + bi).
// ---------------------------------------------------------------------------
__global__ __launch_bounds__(256) void affine_kernel(uint8_t* __restrict__ wsb)
{
    bfraw* base = (bfraw*)wsb;
    const float* sc = (const float*)(wsb + SUM_OFF_B) + 640;
    const float* bi = sc + 320;
    size_t i8 = ((size_t)blockIdx.x * 256 + threadIdx.x) * 8;
    bfraw4 v0 = *(bfraw4*)&base[i8];
    bfraw4 v1 = *(bfraw4*)&base[i8 + 4];
    if (i8 < QK_BF) {
        int ch0 = (int)(i8 & 63);
        float4 s0 = *(const float4*)&sc[ch0];
        float4 s1 = *(const float4*)&sc[ch0 + 4];
        float4 c0 = *(const float4*)&bi[ch0];
        float4 c1 = *(const float4*)&bi[ch0 + 4];
        float sa[8] = {s0.x, s0.y, s0.z, s0.w, s1.x, s1.y, s1.z, s1.w};
        float ca[8] = {c0.x, c0.y, c0.z, c0.w, c1.x, c1.y, c1.z, c1.w};
#pragma unroll
        for (int j = 0; j < 4; ++j) {
            v0[j] = f2bf(fmaxf(0.f, fmaf(sa[j],     bf2f(v0[j]), ca[j])));
            v1[j] = f2bf(fmaxf(0.f, fmaf(sa[j + 4], bf2f(v1[j]), ca[j + 4])));
        }
    } else {
        int ch = 64 + (int)(((i8 - QK_BF) >> 12) & 255);
        float s = sc[ch], b = bi[ch];
#pragma unroll
        for (int j = 0; j < 4; ++j) {
            v0[j] = f2bf(fmaxf(0.f, fmaf(s, bf2f(v0[j]), b)));
            v1[j] = f2bf(fmaxf(0.f, fmaf(s, bf2f(v1[j]), b)));
        }
    }
    *(bfraw4*)&base[i8] = v0;
    *(bfraw4*)&base[i8 + 4] = v1;
}

// ---------------------------------------------------------------------------
// Kernel 4: softmax stats, k-split x4.  Stores partial (m, l) in log2 domain:
// mpart[ks][b][n], lpart[ks][b][n].  Grid 1024 = 4b x 4ks x 64 q-groups.
// ---------------------------------------------------------------------------
__global__ __launch_bounds__(256, 4) void mlpass_kernel(uint8_t* __restrict__ wsb)
{
    const bfraw* qkt = (const bfraw*)wsb;
    float* mpart = (float*)(wsb + ML_OFF_B);
    float* lpart = mpart + 65536;
    const int id = blockIdx.x;
    const int b = id & 3;
    const int ks = (id >> 2) & 3;
    const int n0q = (id >> 4) << 6;
    const int tid = threadIdx.x;
    const int w = tid >> 6, l = tid & 63, lq = l & 15, lg = l >> 4;
    const bfraw* qkb = qkt + ((size_t)b * N_ << 6);
    const short8 qfrag = *(const short8*)&qkb[((size_t)(n0q + w * 16 + lq) << 6) + lg * 8];

    float mx = -1e30f, sum = 0.f;
    const int kbeg = ks * 1024;
    for (int n0k = kbeg; n0k < kbeg + 1024; n0k += 128) {
        float4v st[8];
#pragma unroll
        for (int kt = 0; kt < 8; ++kt) {
            short8 kf = *(const short8*)&qkb[((size_t)(n0k + kt * 16 + lq) << 6) + 32 + lg * 8];
            float4v z = {0.f, 0.f, 0.f, 0.f};
            st[kt] = __builtin_amdgcn_mfma_f32_16x16x32_bf16(kf, qfrag, z, 0, 0, 0);
        }
        float m1 = st[0][0];
#pragma unroll
        for (int kt = 0; kt < 8; ++kt)
#pragma unroll
            for (int r = 0; r < 4; ++r) m1 = fmaxf(m1, st[kt][r]);
        float nm = fmaxf(mx, m1);
        float ae = 0.f;
#pragma unroll
        for (int kt = 0; kt < 8; ++kt)
#pragma unroll
            for (int r = 0; r < 4; ++r) ae += EXP2(st[kt][r] - nm);
        sum = sum * EXP2(mx - nm) + ae;
        mx = nm;
    }
#pragma unroll
    for (int m = 16; m < 64; m <<= 1) {
        float mo = __shfl_xor(mx, m);
        float so = __shfl_xor(sum, m);
        float nm = fmaxf(mx, mo);
        sum = sum * EXP2(mx - nm) + so * EXP2(mo - nm);
        mx = nm;
    }
    if (lg == 0) {
        int idx = ks * 16384 + b * N_ + n0q + w * 16 + lq;
        mpart[idx] = mx;
        lpart[idx] = sum;
    }
}

// ---------------------------------------------------------------------------
// Kernel 5: PV flash, c-split x2, k-split x2.  Grid 1024:
// id&3=b, (id>>2)&1=c-half, (id>>3)&1=k-half, id>>4=q-group.
// 16 iters of TK=128; p=exp2(s-ml) single v_exp; P packed via v_perm;
// epilogue atomically adds partial O into out (pre-initialized to x).
// ---------------------------------------------------------------------------
__global__ __launch_bounds__(256, 4) void flash_kernel(
    const uint8_t* __restrict__ wsb, float* __restrict__ out)
{
    const bfraw* qkt = (const bfraw*)wsb;
    const bfraw* db  = (const bfraw*)(wsb + D_OFF_B);
    const float* mpart = (const float*)(wsb + ML_OFF_B);
    const float* lpart = mpart + 65536;
    __shared__ bfraw Pl[2][64 * 128];

    const int id  = blockIdx.x;
    const int b   = id & 3;
    const int hf  = (id >> 2) & 1;
    const int kh  = (id >> 3) & 1;
    const int n0q = (id >> 4) << 6;
    const int tid = threadIdx.x;
    const int w   = tid >> 6;
    const int l   = tid & 63;
    const int lq  = l & 15;
    const int lg  = l >> 4;
    const int sw  = lq & 7;
    const int k0  = kh << 11;            // 0 or 2048

    const bfraw* qkb   = qkt + ((size_t)b * N_ << 6);
    const bfraw* dbase = db + ((size_t)b * C_ + hf * 128) * N_;

    const short8 qfrag = *(const short8*)&qkb[((size_t)(n0q + w * 16 + lq) << 6) + lg * 8];
    // merge 4 partial (m,l) -> ml for this q (log2 domain)
    float mlq;
    {
        int qi = b * N_ + n0q + w * 16 + lq;
        float M = -1e30f, ms[4], ls[4];
#pragma unroll
        for (int s = 0; s < 4; ++s) {
            ms[s] = mpart[s * 16384 + qi];
            ls[s] = lpart[s * 16384 + qi];
            M = fmaxf(M, ms[s]);
        }
        float L = 0.f;
#pragma unroll
        for (int s = 0; s < 4; ++s) L += ls[s] * EXP2(ms[s] - M);
        mlq = M + __log2f(L);
    }

    float4v acc[2][4];
#pragma unroll
    for (int i = 0; i < 2; ++i)
#pragma unroll
        for (int j = 0; j < 4; ++j) acc[i][j] = (float4v){0.f, 0.f, 0.f, 0.f};

    short8 kf[8], df[2][4];
#pragma unroll
    for (int kt = 0; kt < 8; ++kt)
        kf[kt] = *(const short8*)&qkb[((size_t)(k0 + kt * 16 + lq) << 6) + 32 + lg * 8];
#pragma unroll
    for (int ct = 0; ct < 2; ++ct) {
        int c = (ct * 4 + w) * 16 + lq;
#pragma unroll
        for (int ch = 0; ch < 4; ++ch)
            df[ct][ch] = *(const short8*)&dbase[(size_t)c * N_ + k0 + ch * 32 + lg * 8];
    }

    for (int it = 0; it < 16; ++it) {
        const int ib = it & 1;
        const int nk = k0 + ((((it + 1) & 15)) << 7);
        float4v st[8];
#pragma unroll
        for (int kt = 0; kt < 8; ++kt) {
            float4v z = {0.f, 0.f, 0.f, 0.f};
            st[kt] = __builtin_amdgcn_mfma_f32_16x16x32_bf16(kf[kt], qfrag, z, 0, 0, 0);
        }
#pragma unroll
        for (int kt = 0; kt < 8; ++kt)
            kf[kt] = *(const short8*)&qkb[((size_t)(nk + kt * 16 + lq) << 6) + 32 + lg * 8];
        // p = exp2(s - ml); pack pairs with v_perm; swizzled LDS write (8B)
#pragma unroll
        for (int kt = 0; kt < 8; ++kt) {
            float e0 = EXP2(st[kt][0] - mlq);
            float e1 = EXP2(st[kt][1] - mlq);
            float e2 = EXP2(st[kt][2] - mlq);
            float e3 = EXP2(st[kt][3] - mlq);
            uint2 pd = {pack2(e0, e1), pack2(e2, e3)};
            int g = (2 * kt + (lg >> 1)) ^ sw;
            *(uint2*)&Pl[ib][(w * 16 + lq) * 128 + g * 8 + (lg & 1) * 4] = pd;
        }
        __syncthreads();
#pragma unroll
        for (int ch = 0; ch < 4; ++ch) {
            short8 bfr[4];
#pragma unroll
            for (int qt = 0; qt < 4; ++qt) {
                int g = (4 * ch + lg) ^ sw;
                bfr[qt] = *(const short8*)&Pl[ib][(qt * 16 + lq) * 128 + g * 8];
            }
#pragma unroll
            for (int ct = 0; ct < 2; ++ct)
#pragma unroll
                for (int qt = 0; qt < 4; ++qt)
                    acc[ct][qt] = __builtin_amdgcn_mfma_f32_16x16x32_bf16(df[ct][ch], bfr[qt], acc[ct][qt], 0, 0, 0);
#pragma unroll
            for (int ct = 0; ct < 2; ++ct) {
                int c = (ct * 4 + w) * 16 + lq;
                df[ct][ch] = *(const short8*)&dbase[(size_t)c * N_ + nk + ch * 32 + lg * 8];
            }
        }
    }
    // ---- epilogue: out += partial O (out pre-initialized to x) ----
#pragma unroll
    for (int ct = 0; ct < 2; ++ct)
#pragma unroll
        for (int r = 0; r < 4; ++r) {
            int c = hf * 128 + (ct * 4 + w) * 16 + lg * 4 + r;
            size_t base = ((size_t)b * C_ + c) * N_ + n0q;
#pragma unroll
            for (int qt = 0; qt < 4; ++qt) {
                size_t idx = base + qt * 16 + lq;
                unsafeAtomicAdd(&out[idx], acc[ct][qt][r]);
            }
        }
}

extern "C" void kernel_launch(void* const* d_in, const int* in_sizes, int n_in,
                              void* d_out, int out_size, void* d_ws, size_t ws_size,
                              hipStream_t stream) {
    (void)in_sizes; (void)n_in; (void)out_size; (void)ws_size;
    const float* x  = (const float*)d_in[0];
    const float* w1 = (const float*)d_in[1];
    const float* w2 = (const float*)d_in[2];
    const float* w3 = (const float*)d_in[3];
    const float* g1 = (const float*)d_in[4];
    const float* b1 = (const float*)d_in[5];
    const float* g2 = (const float*)d_in[6];
    const float* b2 = (const float*)d_in[7];
    const float* g3 = (const float*)d_in[8];
    const float* b3 = (const float*)d_in[9];
    uint8_t* wsb = (uint8_t*)d_ws;
    float* sums = (float*)(wsb + SUM_OFF_B);
    float* outp = (float*)d_out;

    zero_kernel<<<1, 256, 0, stream>>>(sums);
    initout_kernel<<<D_BF / 1024, 256, 0, stream>>>(x, outp);
    wsplit_kernel<<<80, 256, 0, stream>>>(w1, w2, w3, wsb);
    xtsplit_kernel<<<1024, 256, 0, stream>>>(x, wsb);
    ygemm_kernel<<<dim3(128, 5), 256, 0, stream>>>(wsb);
    finalize_kernel<<<1, 320, 0, stream>>>(g1, b1, g2, b2, g3, b3, sums);
    affine_kernel<<<(QK_BF + D_BF) / 8 / 256, 256, 0, stream>>>(wsb);
    mlpass_kernel<<<1024, 256, 0, stream>>>(wsb);
    flash_kernel<<<1024, 256, 0, stream>>>(wsb, outp);
}

// Round 7
// 209.444 us; speedup vs baseline: 1.4776x; 1.4776x over previous
//
#include <hip/hip_runtime.h>
#include <cstddef>
#include <cstdint>

#define B_ 4
#define C_ 256
#define N_ 4096
/* frag-layout operand planes:
   qf [b][256 ntile][64 lane][8]  bf16  (q channels 0..31, log2e folded via BN)
   kf [b][256 ntile][64 lane][8]  bf16  (k channels 32..63)
   df [b][16 ctile][128 nchunk][64 lane][8] bf16                              */
#define KF_OFF_B  ((size_t)1024 * 1024)
#define DF_OFF_B  ((size_t)2 * 1024 * 1024)
#define SUM_OFF_B ((size_t)10 * 1024 * 1024)       /* sum[320],sumsq[320],sc[320],bi[320] */
#define ML_OFF_B  (SUM_OFF_B + 1280 * 4)           /* mpart[4][16384], lpart[4][16384] */
#define XH_OFF_B  (ML_OFF_B + 524288)              /* xt hi [b][n][256] bf16: 8 MB */
#define XL_OFF_B  (XH_OFF_B + (size_t)8 * 1024 * 1024)
#define WH_OFF_B  (XL_OFF_B + (size_t)8 * 1024 * 1024)
#define WL_OFF_B  (WH_OFF_B + 163840)
#define LOG2E 1.4426950408889634f

typedef unsigned short bfraw;
typedef __attribute__((ext_vector_type(8))) short short8;
typedef __attribute__((ext_vector_type(4))) float float4v;
typedef __attribute__((ext_vector_type(4))) bfraw bfraw4;

__device__ inline bfraw f2bf(float f) {
    union { float f; uint32_t u; } c; c.f = f;
    uint32_t u = c.u;
    u += 0x7fffu + ((u >> 16) & 1u);     // RNE
    return (bfraw)(u >> 16);
}
__device__ inline float bf2f(bfraw h) {
    union { uint32_t u; float f; } c; c.u = ((uint32_t)h) << 16;
    return c.f;
}
#if __has_builtin(__builtin_amdgcn_exp2f)
__device__ inline float EXP2(float x) { return __builtin_amdgcn_exp2f(x); }
#else
__device__ inline float EXP2(float x) { return exp2f(x); }
#endif
__device__ inline uint32_t pack2(float a, float b) {
    union { float f; uint32_t u; } ca, cb; ca.f = a; cb.f = b;
#if __has_builtin(__builtin_amdgcn_perm)
    return __builtin_amdgcn_perm(cb.u + 0x8000u, ca.u + 0x8000u, 0x07060302u);
#else
    return ((ca.u + 0x8000u) >> 16) | ((cb.u + 0x8000u) & 0xffff0000u);
#endif
}

// ---------------------------------------------------------------------------
__global__ void zero_kernel(float* __restrict__ sums) {
    for (int i = threadIdx.x; i < 640; i += 256) sums[i] = 0.f;
}

// ---------------------------------------------------------------------------
// split w into bf16 hi/lo planes [320][256]
// ---------------------------------------------------------------------------
__global__ __launch_bounds__(256) void wsplit_kernel(
    const float* __restrict__ w1, const float* __restrict__ w2,
    const float* __restrict__ w3, uint8_t* __restrict__ wsb)
{
    bfraw* wh = (bfraw*)(wsb + WH_OFF_B);
    bfraw* wl = (bfraw*)(wsb + WL_OFF_B);
    int idx4 = (blockIdx.x * 256 + threadIdx.x) * 4;
    int ch = idx4 >> 8, k = idx4 & 255;
    const float* wr = (ch < 32) ? (w1 + ch * C_)
                      : (ch < 64) ? (w2 + (ch - 32) * C_)
                                  : (w3 + (ch - 64) * C_);
    float4 v = *(const float4*)&wr[k];
    float va[4] = {v.x, v.y, v.z, v.w};
    bfraw4 h, l;
#pragma unroll
    for (int j = 0; j < 4; ++j) {
        h[j] = f2bf(va[j]);
        l[j] = f2bf(va[j] - bf2f(h[j]));
    }
    *(bfraw4*)&wh[idx4] = h;
    *(bfraw4*)&wl[idx4] = l;
}

// ---------------------------------------------------------------------------
// transpose+split x -> xt hi/lo [b][n][256] bf16
// ---------------------------------------------------------------------------
__global__ __launch_bounds__(256) void xtsplit_kernel(
    const float* __restrict__ x, uint8_t* __restrict__ wsb)
{
    __shared__ float Ls[64][65];
    bfraw* xh = (bfraw*)(wsb + XH_OFF_B);
    bfraw* xl = (bfraw*)(wsb + XL_OFF_B);
    const int id = blockIdx.x;
    const int b  = id >> 8;
    const int c0 = ((id >> 6) & 3) << 6;
    const int n0 = (id & 63) << 6;
    const int t  = threadIdx.x;
    {
        int cl = t >> 4, nc = (t & 15) << 2;
#pragma unroll
        for (int i = 0; i < 4; ++i) {
            float4 v = *(const float4*)&x[((size_t)b * C_ + c0 + cl + i * 16) * N_ + n0 + nc];
            Ls[cl + i * 16][nc + 0] = v.x;
            Ls[cl + i * 16][nc + 1] = v.y;
            Ls[cl + i * 16][nc + 2] = v.z;
            Ls[cl + i * 16][nc + 3] = v.w;
        }
    }
    __syncthreads();
    int nl = t >> 2, seg = t & 3;
    bfraw hb[16], lb[16];
#pragma unroll
    for (int j = 0; j < 16; ++j) {
        float v = Ls[seg * 16 + j][nl];
        bfraw h = f2bf(v);
        hb[j] = h;
        lb[j] = f2bf(v - bf2f(h));
    }
    size_t base = ((size_t)b * N_ + n0 + nl) * 256 + c0 + seg * 16;
    *(short8*)&xh[base]     = *(short8*)&hb[0];
    *(short8*)&xh[base + 8] = *(short8*)&hb[8];
    *(short8*)&xl[base]     = *(short8*)&lb[0];
    *(short8*)&xl[base + 8] = *(short8*)&lb[8];
}

// ---------------------------------------------------------------------------
// MFMA ygemm (3-term bf16 split); epilogue stores q/k/d in FRAG LAYOUT.
// ---------------------------------------------------------------------------
__global__ __launch_bounds__(256, 2) void ygemm_kernel(uint8_t* __restrict__ wsb)
{
    const bfraw* xh = (const bfraw*)(wsb + XH_OFF_B);
    const bfraw* xl = (const bfraw*)(wsb + XL_OFF_B);
    const bfraw* wh = (const bfraw*)(wsb + WH_OFF_B);
    const bfraw* wl = (const bfraw*)(wsb + WL_OFF_B);
    bfraw* qf  = (bfraw*)wsb;
    bfraw* kfp = (bfraw*)(wsb + KF_OFF_B);
    bfraw* dfp = (bfraw*)(wsb + DF_OFF_B);
    float* sums  = (float*)(wsb + SUM_OFF_B);
    float* sumsq = sums + 320;
    __shared__ float redS[4][64], redQ[4][64];

    const int bx = blockIdx.x;
    const int by = blockIdx.y;
    const int b  = bx >> 5;
    const int n0 = (bx << 7) & (N_ - 1);
    const int t = threadIdx.x, w = t >> 6, l = t & 63, lq = l & 15, lg = l >> 4;
    const int nw = n0 + w * 32;

    float4v acc[4][2];
#pragma unroll
    for (int i = 0; i < 4; ++i)
#pragma unroll
        for (int j = 0; j < 2; ++j) acc[i][j] = (float4v){0.f, 0.f, 0.f, 0.f};

    for (int s = 0; s < 8; ++s) {
        const int k0 = s * 32;
        short8 ah[4], al[4], bh[2], bl[2];
#pragma unroll
        for (int ct = 0; ct < 4; ++ct) {
            size_t off = (size_t)(by * 64 + ct * 16 + lq) * 256 + k0 + lg * 8;
            ah[ct] = *(const short8*)&wh[off];
            al[ct] = *(const short8*)&wl[off];
        }
#pragma unroll
        for (int nt = 0; nt < 2; ++nt) {
            size_t off = ((size_t)b * N_ + nw + nt * 16 + lq) * 256 + k0 + lg * 8;
            bh[nt] = *(const short8*)&xh[off];
            bl[nt] = *(const short8*)&xl[off];
        }
#pragma unroll
        for (int ct = 0; ct < 4; ++ct)
#pragma unroll
            for (int nt = 0; nt < 2; ++nt) {
                acc[ct][nt] = __builtin_amdgcn_mfma_f32_16x16x32_bf16(ah[ct], bh[nt], acc[ct][nt], 0, 0, 0);
                acc[ct][nt] = __builtin_amdgcn_mfma_f32_16x16x32_bf16(al[ct], bh[nt], acc[ct][nt], 0, 0, 0);
                acc[ct][nt] = __builtin_amdgcn_mfma_f32_16x16x32_bf16(ah[ct], bl[nt], acc[ct][nt], 0, 0, 0);
            }
    }
#pragma unroll
    for (int ct = 0; ct < 4; ++ct) {
        float sv[4], qv[4];
#pragma unroll
        for (int r = 0; r < 4; ++r) {
            float a0 = acc[ct][0][r], a1 = acc[ct][1][r];
            sv[r] = a0 + a1;
            qv[r] = a0 * a0 + a1 * a1;
#pragma unroll
            for (int m = 1; m < 16; m <<= 1) {
                sv[r] += __shfl_xor(sv[r], m);
                qv[r] += __shfl_xor(qv[r], m);
            }
        }
        if (lq == 0) {
#pragma unroll
            for (int r = 0; r < 4; ++r) {
                redS[w][ct * 16 + lg * 4 + r] = sv[r];
                redQ[w][ct * 16 + lg * 4 + r] = qv[r];
            }
        }
    }
    __syncthreads();
    if (t < 64) {
        float s = redS[0][t] + redS[1][t] + redS[2][t] + redS[3][t];
        float q = redQ[0][t] + redQ[1][t] + redQ[2][t] + redQ[3][t];
        atomicAdd(&sums[by * 64 + t], s);
        atomicAdd(&sumsq[by * 64 + t], q);
    }
    if (by == 0) {
        // q/k frag layout: tile = b*256 + n>>4; lane = (n&15)|(((c>>3)&3)<<4); j = c&7
#pragma unroll
        for (int ct = 0; ct < 4; ++ct)
#pragma unroll
            for (int nt = 0; nt < 2; ++nt)
#pragma unroll
                for (int r = 0; r < 4; ++r) {
                    int c = ct * 16 + lg * 4 + r;
                    int n = nw + nt * 16 + lq;
                    size_t addr = ((size_t)(b << 8) + (n >> 4)) * 512
                                + (size_t)(((n & 15) | (((c >> 3) & 3) << 4)) << 3) + (c & 7);
                    bfraw v = f2bf(acc[ct][nt][r]);
                    if (c < 32) qf[addr] = v; else kfp[addr] = v;
                }
    } else {
        // d frag layout: ctile = cg>>4; chunk = n>>5; lane = (cg&15)|(((n>>3)&3)<<4); j = n&7
#pragma unroll
        for (int ct = 0; ct < 4; ++ct)
#pragma unroll
            for (int nt = 0; nt < 2; ++nt)
#pragma unroll
                for (int r = 0; r < 4; ++r) {
                    int cg = (by - 1) * 64 + ct * 16 + lg * 4 + r;
                    int n = nw + nt * 16 + lq;
                    size_t addr = (((size_t)(b << 4) + (cg >> 4)) * 128 + (n >> 5)) * 512
                                + (size_t)(((cg & 15) | (((n >> 3) & 3) << 4)) << 3) + (n & 7);
                    dfp[addr] = f2bf(acc[ct][nt][r]);
                }
    }
}

// ---------------------------------------------------------------------------
// finalize BN -> folded scale/bias; q channels pre-scaled by log2(e).
// ---------------------------------------------------------------------------
__global__ void finalize_kernel(
    const float* __restrict__ g1, const float* __restrict__ b1,
    const float* __restrict__ g2, const float* __restrict__ b2,
    const float* __restrict__ g3, const float* __restrict__ b3,
    float* __restrict__ sums)
{
    int ch = threadIdx.x;
    if (ch >= 320) return;
    const float inv = 1.0f / (float)(B_ * N_);
    float mean = sums[ch] * inv;
    float var = sums[320 + ch] * inv - mean * mean;
    float g, bb;
    if (ch < 32)      { g = g1[ch];      bb = b1[ch]; }
    else if (ch < 64) { g = g2[ch - 32]; bb = b2[ch - 32]; }
    else              { g = g3[ch - 64]; bb = b3[ch - 64]; }
    float sc = g * rsqrtf(var + 1e-5f);
    float bi = bb - sc * mean;
    if (ch < 32) { sc *= LOG2E; bi *= LOG2E; }
    sums[640 + ch] = sc;
    sums[960 + ch] = bi;
}

// ---------------------------------------------------------------------------
// in-place bf16 relu(sc*y + bi) over frag-layout planes.
// qf: c = seg*8 + j (seg=(i>>7)&3, 8 consecutive channels per group)
// kf: c = 32 + seg*8 + j
// df: c = 64 + ctile*16 + ((i>>3)&15)  (uniform per group)
// ---------------------------------------------------------------------------
__global__ __launch_bounds__(256) void affine_kernel(uint8_t* __restrict__ wsb)
{
    bfraw* base = (bfraw*)wsb;
    const float* sc = (const float*)(wsb + SUM_OFF_B) + 640;
    const float* bi = sc + 320;
    size_t i8 = ((size_t)blockIdx.x * 256 + threadIdx.x) * 8;
    bfraw4 v0 = *(bfraw4*)&base[i8];
    bfraw4 v1 = *(bfraw4*)&base[i8 + 4];
    if (i8 < 1048576) {                          // qf or kf
        int ch0 = (((int)(i8 >> 7)) & 3) * 8 + ((i8 < 524288) ? 0 : 32);
        float4 s0 = *(const float4*)&sc[ch0];
        float4 s1 = *(const float4*)&sc[ch0 + 4];
        float4 c0 = *(const float4*)&bi[ch0];
        float4 c1 = *(const float4*)&bi[ch0 + 4];
        float sa[8] = {s0.x, s0.y, s0.z, s0.w, s1.x, s1.y, s1.z, s1.w};
        float ca[8] = {c0.x, c0.y, c0.z, c0.w, c1.x, c1.y, c1.z, c1.w};
#pragma unroll
        for (int j = 0; j < 4; ++j) {
            v0[j] = f2bf(fmaxf(0.f, fmaf(sa[j],     bf2f(v0[j]), ca[j])));
            v1[j] = f2bf(fmaxf(0.f, fmaf(sa[j + 4], bf2f(v1[j]), ca[j + 4])));
        }
    } else {                                     // df
        size_t rel = i8 - 1048576;
        int ch = 64 + (((int)(rel >> 16)) & 15) * 16 + (((int)(rel >> 3)) & 15);
        float s = sc[ch], b = bi[ch];
#pragma unroll
        for (int j = 0; j < 4; ++j) {
            v0[j] = f2bf(fmaxf(0.f, fmaf(s, bf2f(v0[j]), b)));
            v1[j] = f2bf(fmaxf(0.f, fmaf(s, bf2f(v1[j]), b)));
        }
    }
    *(bfraw4*)&base[i8] = v0;
    *(bfraw4*)&base[i8 + 4] = v1;
}

// ---------------------------------------------------------------------------
// softmax stats, k-split x4, frag-layout coalesced loads.
// Grid 1024 = 4b x 4ks x 64 q-groups of 64.
// ---------------------------------------------------------------------------
__global__ __launch_bounds__(256, 4) void mlpass_kernel(uint8_t* __restrict__ wsb)
{
    const bfraw* qf  = (const bfraw*)wsb;
    const bfraw* kfp = (const bfraw*)(wsb + KF_OFF_B);
    float* mpart = (float*)(wsb + ML_OFF_B);
    float* lpart = mpart + 65536;
    const int id = blockIdx.x;
    const int b = id & 3;
    const int ks = (id >> 2) & 3;
    const int n0q = (id >> 4) << 6;
    const int tid = threadIdx.x;
    const int w = tid >> 6, l = tid & 63, lq = l & 15, lg = l >> 4;
    const short8 qfrag = *(const short8*)&qf[((size_t)(b * 256 + (n0q >> 4) + w)) * 512 + l * 8];

    float mx = -1e30f, sum = 0.f;
    const int tbeg = b * 256 + ks * 64;          // k-tile range: 64 tiles of 16
    for (int tk = tbeg; tk < tbeg + 64; tk += 8) {
        float4v st[8];
#pragma unroll
        for (int kt = 0; kt < 8; ++kt) {
            short8 kf = *(const short8*)&kfp[((size_t)(tk + kt)) * 512 + l * 8];
            float4v z = {0.f, 0.f, 0.f, 0.f};
            st[kt] = __builtin_amdgcn_mfma_f32_16x16x32_bf16(kf, qfrag, z, 0, 0, 0);
        }
        float m1 = st[0][0];
#pragma unroll
        for (int kt = 0; kt < 8; ++kt)
#pragma unroll
            for (int r = 0; r < 4; ++r) m1 = fmaxf(m1, st[kt][r]);
        float nm = fmaxf(mx, m1);
        float ae = 0.f;
#pragma unroll
        for (int kt = 0; kt < 8; ++kt)
#pragma unroll
            for (int r = 0; r < 4; ++r) ae += EXP2(st[kt][r] - nm);
        sum = sum * EXP2(mx - nm) + ae;
        mx = nm;
    }
#pragma unroll
    for (int m = 16; m < 64; m <<= 1) {
        float mo = __shfl_xor(mx, m);
        float so = __shfl_xor(sum, m);
        float nm = fmaxf(mx, mo);
        sum = sum * EXP2(mx - nm) + so * EXP2(mo - nm);
        mx = nm;
    }
    if (lg == 0) {
        int idx = ks * 16384 + b * N_ + n0q + w * 16 + lq;
        mpart[idx] = mx;
        lpart[idx] = sum;
    }
}

// ---------------------------------------------------------------------------
// PV flash: TQ=32, c-split x2, q-split -> grid 1024 (4 blocks/CU), NO atomics.
// id&3=b, (id>>2)&1=hf, id>>3=q-block of 32.  Waves: qt_loc=w>>1 owns scores
// for its 16-q frag-tile over k-half ks_loc=w&1.  TK=128, 1 barrier/iter,
// double-buffered XOR-swizzled P.  All global fragment loads coalesced 1KB.
// ---------------------------------------------------------------------------
__global__ __launch_bounds__(256, 4) void flash_kernel(
    const float* __restrict__ x, const uint8_t* __restrict__ wsb,
    float* __restrict__ out)
{
    const bfraw* qf  = (const bfraw*)wsb;
    const bfraw* kfp = (const bfraw*)(wsb + KF_OFF_B);
    const bfraw* dfp = (const bfraw*)(wsb + DF_OFF_B);
    const float* mpart = (const float*)(wsb + ML_OFF_B);
    const float* lpart = mpart + 65536;
    __shared__ bfraw Pl[2][32 * 128];

    const int id  = blockIdx.x;
    const int b   = id & 3;
    const int hf  = (id >> 2) & 1;
    const int n0q = (id >> 3) << 5;
    const int tid = threadIdx.x;
    const int w   = tid >> 6;
    const int l   = tid & 63;
    const int lq  = l & 15;
    const int lg  = l >> 4;
    const int sw  = lq & 7;
    const int qt_loc = w >> 1;
    const int ks_loc = w & 1;
    const int ctg0 = hf * 8 + w;                 // ct=0 tile
    const int ctg1 = hf * 8 + 4 + w;             // ct=1 tile

    const short8 qfrag = *(const short8*)&qf[((size_t)(b * 256 + (n0q >> 4) + qt_loc)) * 512 + l * 8];
    float mlq;
    {
        int qi = b * N_ + n0q + qt_loc * 16 + lq;
        float M = -1e30f, ms[4], ls[4];
#pragma unroll
        for (int s = 0; s < 4; ++s) {
            ms[s] = mpart[s * 16384 + qi];
            ls[s] = lpart[s * 16384 + qi];
            M = fmaxf(M, ms[s]);
        }
        float L = 0.f;
#pragma unroll
        for (int s = 0; s < 4; ++s) L += ls[s] * EXP2(ms[s] - M);
        mlq = M + __log2f(L);
    }

    float4v acc[2][2];
#pragma unroll
    for (int i = 0; i < 2; ++i)
#pragma unroll
        for (int j = 0; j < 2; ++j) acc[i][j] = (float4v){0.f, 0.f, 0.f, 0.f};

    short8 kfr[4], dfr[2][4];
#pragma unroll
    for (int kt = 0; kt < 4; ++kt)
        kfr[kt] = *(const short8*)&kfp[((size_t)(b * 256 + ks_loc * 4 + kt)) * 512 + l * 8];
#pragma unroll
    for (int ch = 0; ch < 4; ++ch) {
        dfr[0][ch] = *(const short8*)&dfp[(((size_t)(b * 16 + ctg0)) * 128 + ch) * 512 + l * 8];
        dfr[1][ch] = *(const short8*)&dfp[(((size_t)(b * 16 + ctg1)) * 128 + ch) * 512 + l * 8];
    }

    const int qrow = qt_loc * 16 + lq;
    for (int it = 0; it < 32; ++it) {
        const int ib = it & 1;
        const int nit = (it + 1) & 31;
        // ---- scores (this wave's 16q x 64k quadrant) ----
        float4v st[4];
#pragma unroll
        for (int kt = 0; kt < 4; ++kt) {
            float4v z = {0.f, 0.f, 0.f, 0.f};
            st[kt] = __builtin_amdgcn_mfma_f32_16x16x32_bf16(kfr[kt], qfrag, z, 0, 0, 0);
        }
#pragma unroll
        for (int kt = 0; kt < 4; ++kt)
            kfr[kt] = *(const short8*)&kfp[((size_t)(b * 256 + nit * 8 + ks_loc * 4 + kt)) * 512 + l * 8];
        // ---- p = exp2(s - ml), pack, swizzled LDS write ----
#pragma unroll
        for (int kt = 0; kt < 4; ++kt) {
            float e0 = EXP2(st[kt][0] - mlq);
            float e1 = EXP2(st[kt][1] - mlq);
            float e2 = EXP2(st[kt][2] - mlq);
            float e3 = EXP2(st[kt][3] - mlq);
            uint2 pd = {pack2(e0, e1), pack2(e2, e3)};
            int g = (2 * (ks_loc * 4 + kt) + (lg >> 1)) ^ sw;
            *(uint2*)&Pl[ib][qrow * 128 + g * 8 + (lg & 1) * 4] = pd;
        }
        __syncthreads();
        // ---- PV ----
#pragma unroll
        for (int ch = 0; ch < 4; ++ch) {
            short8 bfr[2];
#pragma unroll
            for (int qt = 0; qt < 2; ++qt) {
                int g = (ch * 4 + lg) ^ sw;
                bfr[qt] = *(const short8*)&Pl[ib][(qt * 16 + lq) * 128 + g * 8];
            }
            acc[0][0] = __builtin_amdgcn_mfma_f32_16x16x32_bf16(dfr[0][ch], bfr[0], acc[0][0], 0, 0, 0);
            acc[0][1] = __builtin_amdgcn_mfma_f32_16x16x32_bf16(dfr[0][ch], bfr[1], acc[0][1], 0, 0, 0);
            acc[1][0] = __builtin_amdgcn_mfma_f32_16x16x32_bf16(dfr[1][ch], bfr[0], acc[1][0], 0, 0, 0);
            acc[1][1] = __builtin_amdgcn_mfma_f32_16x16x32_bf16(dfr[1][ch], bfr[1], acc[1][1], 0, 0, 0);
            dfr[0][ch] = *(const short8*)&dfp[(((size_t)(b * 16 + ctg0)) * 128 + nit * 4 + ch) * 512 + l * 8];
            dfr[1][ch] = *(const short8*)&dfp[(((size_t)(b * 16 + ctg1)) * 128 + nit * 4 + ch) * 512 + l * 8];
        }
    }
    // ---- epilogue: out = x + O ----
#pragma unroll
    for (int ct = 0; ct < 2; ++ct) {
        int ctg = ct ? ctg1 : ctg0;
#pragma unroll
        for (int r = 0; r < 4; ++r) {
            int c = ctg * 16 + lg * 4 + r;
            size_t base = ((size_t)b * C_ + c) * N_ + n0q;
#pragma unroll
            for (int qt = 0; qt < 2; ++qt) {
                size_t idx = base + qt * 16 + lq;
                out[idx] = x[idx] + acc[ct][qt][r];
            }
        }
    }
}

extern "C" void kernel_launch(void* const* d_in, const int* in_sizes, int n_in,
                              void* d_out, int out_size, void* d_ws, size_t ws_size,
                              hipStream_t stream) {
    (void)in_sizes; (void)n_in; (void)out_size; (void)ws_size;
    const float* x  = (const float*)d_in[0];
    const float* w1 = (const float*)d_in[1];
    const float* w2 = (const float*)d_in[2];
    const float* w3 = (const float*)d_in[3];
    const float* g1 = (const float*)d_in[4];
    const float* b1 = (const float*)d_in[5];
    const float* g2 = (const float*)d_in[6];
    const float* b2 = (const float*)d_in[7];
    const float* g3 = (const float*)d_in[8];
    const float* b3 = (const float*)d_in[9];
    uint8_t* wsb = (uint8_t*)d_ws;
    float* sums = (float*)(wsb + SUM_OFF_B);
    float* outp = (float*)d_out;

    zero_kernel<<<1, 256, 0, stream>>>(sums);
    wsplit_kernel<<<80, 256, 0, stream>>>(w1, w2, w3, wsb);
    xtsplit_kernel<<<1024, 256, 0, stream>>>(x, wsb);
    ygemm_kernel<<<dim3(128, 5), 256, 0, stream>>>(wsb);
    finalize_kernel<<<1, 320, 0, stream>>>(g1, b1, g2, b2, g3, b3, sums);
    affine_kernel<<<2560, 256, 0, stream>>>(wsb);
    mlpass_kernel<<<1024, 256, 0, stream>>>(wsb);
    flash_kernel<<<1024, 256, 0, stream>>>(x, wsb, outp);
}